// Round 1
// baseline (507.221 us; speedup 1.0000x reference)
//
#include <hip/hip_runtime.h>
#include <hip/hip_bf16.h>
#include <stdint.h>

// MHA forward: B=2, S=2048, D=2048, H=16, DK=128. mask is all-ones (unused by reference).
#define B_  2
#define S_  2048
#define D_  2048
#define H_  16
#define DK_ 128
#define E3_ 6144   // 3*D

typedef __attribute__((ext_vector_type(8))) __bf16 bf16x8;
typedef __attribute__((ext_vector_type(4))) __bf16 bf16x4;
typedef __attribute__((ext_vector_type(4))) float f32x4;

static __device__ __forceinline__ f32x4 mfma16(bf16x8 a, bf16x8 b, f32x4 c) {
  return __builtin_amdgcn_mfma_f32_16x16x32_bf16(a, b, c, 0, 0, 0);
}

// ---------------- f32 -> bf16 convert (vectorized, grid-stride) ----------------
__global__ __launch_bounds__(256) void cvt_f32_bf16(const float* __restrict__ in,
                                                    __bf16* __restrict__ out, int n) {
  int i = (blockIdx.x * 256 + threadIdx.x) * 4;
  int stride = gridDim.x * 256 * 4;
  for (; i < n; i += stride) {
    float4 v = *reinterpret_cast<const float4*>(in + i);
    bf16x4 o;
    o[0] = (__bf16)v.x; o[1] = (__bf16)v.y; o[2] = (__bf16)v.z; o[3] = (__bf16)v.w;
    *reinterpret_cast<bf16x4*>(out + i) = o;
  }
}

// ---------------- GEMM: C[M][N] = A[M][K] * Bw[N][K]^T + bias ----------------
// 128x128 tile, BK=64, 4 waves (2x2), each wave 64x64 (4x4 frags of 16x16x32).
// LDS XOR-swizzle: phys = (row*128 + colb) ^ ((row&7)<<4)  (conflict-free b128 reads)
template <bool OUT_BF16>
__global__ __launch_bounds__(256) void gemm_bt(const __bf16* __restrict__ A,
                                               const __bf16* __restrict__ Bw,
                                               const float* __restrict__ bias,
                                               void* __restrict__ Cout,
                                               int M, int N, int K) {
  __shared__ unsigned char smem[32768];  // As 16KB | Bs 16KB
  const int tid = threadIdx.x;
  const int lane = tid & 63;
  const int w = tid >> 6;
  const int wm = w >> 1, wn = w & 1;
  const int g = lane >> 4, l15 = lane & 15;

  // XCD-aware swizzle (nwg % 8 == 0 for both our launches -> bijective)
  int nwg = gridDim.x * gridDim.y;
  int wgid = blockIdx.y * gridDim.x + blockIdx.x;
  int cpx = nwg >> 3;
  int swz = (wgid & 7) * cpx + (wgid >> 3);
  int bx = swz % gridDim.x;
  int by = swz / gridDim.x;
  const int m0 = by * 128, n0 = bx * 128;

  f32x4 acc[4][4] = {};

  for (int k0 = 0; k0 < K; k0 += 64) {
    __syncthreads();
    // stage A,B tiles: 128 rows x 64 cols bf16 = 1024 granules of 16B each; 4/thread
    int4 ra[4], rb[4];
#pragma unroll
    for (int p = 0; p < 4; ++p) {
      int gran = p * 256 + tid;
      int row = gran >> 3, slot = gran & 7;
      ra[p] = *reinterpret_cast<const int4*>(A + (size_t)(m0 + row) * K + k0 + slot * 8);
      rb[p] = *reinterpret_cast<const int4*>(Bw + (size_t)(n0 + row) * K + k0 + slot * 8);
    }
#pragma unroll
    for (int p = 0; p < 4; ++p) {
      int gran = p * 256 + tid;
      int row = gran >> 3, slot = gran & 7;
      int phys = (row * 128 + slot * 16) ^ ((row & 7) << 4);
      *reinterpret_cast<int4*>(&smem[phys]) = ra[p];
      *reinterpret_cast<int4*>(&smem[16384 + phys]) = rb[p];
    }
    __syncthreads();

#pragma unroll
    for (int kc = 0; kc < 2; ++kc) {
      bf16x8 af[4], bfr[4];
#pragma unroll
      for (int i = 0; i < 4; ++i) {
        int rowa = wm * 64 + i * 16 + l15;
        int pa = (rowa * 128 + kc * 64 + g * 16) ^ ((rowa & 7) << 4);
        af[i] = *reinterpret_cast<const bf16x8*>(&smem[pa]);
        int rowb = wn * 64 + i * 16 + l15;
        int pb = (rowb * 128 + kc * 64 + g * 16) ^ ((rowb & 7) << 4);
        bfr[i] = *reinterpret_cast<const bf16x8*>(&smem[16384 + pb]);
      }
#pragma unroll
      for (int i = 0; i < 4; ++i)
#pragma unroll
        for (int j = 0; j < 4; ++j)
          acc[i][j] = mfma16(af[i], bfr[j], acc[i][j]);
    }
  }

  // epilogue: C/D layout row=(lane>>4)*4+r, col=lane&15
  float bv[4];
#pragma unroll
  for (int j = 0; j < 4; ++j) bv[j] = bias[n0 + wn * 64 + j * 16 + l15];
#pragma unroll
  for (int i = 0; i < 4; ++i)
#pragma unroll
    for (int j = 0; j < 4; ++j)
#pragma unroll
      for (int r = 0; r < 4; ++r) {
        int grow = m0 + wm * 64 + i * 16 + g * 4 + r;
        int gcol = n0 + wn * 64 + j * 16 + l15;
        float v = acc[i][j][r] + bv[j];
        if constexpr (OUT_BF16)
          reinterpret_cast<__bf16*>(Cout)[(size_t)grow * N + gcol] = (__bf16)v;
        else
          reinterpret_cast<float*>(Cout)[(size_t)grow * N + gcol] = v;
      }
}

// ---------------- V transpose: vt[(b*H+h)*DK + d][s] = qkv[(b*S+s)*6144 + h*384+256+d] ----
__global__ __launch_bounds__(256) void transpose_v(const __bf16* __restrict__ qkv,
                                                   __bf16* __restrict__ vt) {
  __shared__ __bf16 tile[64][72];
  int s0 = blockIdx.x * 64, d0 = blockIdx.y * 64, bh = blockIdx.z;
  int b = bh >> 4, h = bh & 15;
  int t = threadIdx.x;
  int rr = t >> 4, cc = (t & 15) * 4;
#pragma unroll
  for (int p = 0; p < 4; ++p) {
    int si = p * 16 + rr;
    bf16x4 v = *reinterpret_cast<const bf16x4*>(
        qkv + (size_t)(b * S_ + s0 + si) * E3_ + h * 384 + 256 + d0 + cc);
    *reinterpret_cast<bf16x4*>(&tile[si][cc]) = v;
  }
  __syncthreads();
#pragma unroll
  for (int p = 0; p < 4; ++p) {
    int di = p * 16 + rr;
    bf16x4 o;
#pragma unroll
    for (int j = 0; j < 4; ++j) o[j] = tile[cc + j][di];
    *reinterpret_cast<bf16x4*>(vt + ((size_t)bh * DK_ + d0 + di) * S_ + s0 + cc) = o;
  }
}

// ---------------- Flash attention ----------------
// grid (S/64, B*H), 256 threads = 4 waves; wave w owns q-rows [qt*64+w*16, +16).
// K tile 64x128 in LDS [64][136] (pad 8), VT tile 128x64 in LDS [128][72] (pad 8),
// P per-wave [16][72]. Online softmax; 16x16x32 MFMA.
__global__ __launch_bounds__(256) void attn_fwd(const __bf16* __restrict__ qkv,
                                                const __bf16* __restrict__ vt,
                                                __bf16* __restrict__ outp) {
  __shared__ unsigned char smem[45056];
  const int K_OFF = 0, VT_OFF = 17408, P_OFF = 35840;
  const int qt = blockIdx.x, bh = blockIdx.y;
  const int b = bh >> 4, h = bh & 15;
  const int tid = threadIdx.x, lane = tid & 63, w = tid >> 6;
  const int g = lane >> 4, l15 = lane & 15;
  const float scale = 0.088388347648318447f;  // 1/sqrt(128)

  // Q fragments (A-operand: row = lane&15, k = (lane>>4)*8+b), held in regs whole kernel
  bf16x8 qf[4];
  {
    int qrow = qt * 64 + w * 16 + l15;
    const __bf16* qb = qkv + (size_t)(b * S_ + qrow) * E3_ + h * 384;
#pragma unroll
    for (int c = 0; c < 4; ++c)
      qf[c] = *reinterpret_cast<const bf16x8*>(qb + c * 32 + g * 8);
  }

  f32x4 o[8] = {};
  float m_run[4], l_run[4];
#pragma unroll
  for (int r = 0; r < 4; ++r) { m_run[r] = -INFINITY; l_run[r] = 0.f; }
  unsigned char* P_base = &smem[P_OFF + w * 2304];

  for (int kt = 0; kt < S_ / 64; ++kt) {
    __syncthreads();
    // stage K (64x128, 16 granules/row) and VT (128x64, 8 granules/row); 4+4 per thread
    int4 kr[4], vr[4];
#pragma unroll
    for (int p = 0; p < 4; ++p) {
      int gran = p * 256 + tid;
      int krow = gran >> 4, kslot = gran & 15;
      kr[p] = *reinterpret_cast<const int4*>(
          qkv + (size_t)(b * S_ + kt * 64 + krow) * E3_ + h * 384 + 128 + kslot * 8);
      int vrow = gran >> 3, vslot = gran & 7;
      vr[p] = *reinterpret_cast<const int4*>(
          vt + ((size_t)bh * DK_ + vrow) * S_ + kt * 64 + vslot * 8);
    }
#pragma unroll
    for (int p = 0; p < 4; ++p) {
      int gran = p * 256 + tid;
      int krow = gran >> 4, kslot = gran & 15;
      *reinterpret_cast<int4*>(&smem[K_OFF + krow * 272 + kslot * 16]) = kr[p];
      int vrow = gran >> 3, vslot = gran & 7;
      *reinterpret_cast<int4*>(&smem[VT_OFF + vrow * 144 + vslot * 16]) = vr[p];
    }
    __syncthreads();

    // QK^T: S-tile 16x64 per wave
    f32x4 sacc[4] = {};
#pragma unroll
    for (int c = 0; c < 4; ++c) {
      bf16x8 kb[4];
#pragma unroll
      for (int j = 0; j < 4; ++j) {
        int row = j * 16 + l15;
        kb[j] = *reinterpret_cast<const bf16x8*>(&smem[K_OFF + row * 272 + c * 64 + g * 16]);
      }
#pragma unroll
      for (int j = 0; j < 4; ++j) sacc[j] = mfma16(qf[c], kb[j], sacc[j]);
    }
#pragma unroll
    for (int j = 0; j < 4; ++j)
#pragma unroll
      for (int r = 0; r < 4; ++r) sacc[j][r] *= scale;

    // online softmax (per lane: 4 rows = g*4+r; 16-lane butterfly covers 64 cols)
    float p_val[4][4];
#pragma unroll
    for (int r = 0; r < 4; ++r) {
      float mt = fmaxf(fmaxf(sacc[0][r], sacc[1][r]), fmaxf(sacc[2][r], sacc[3][r]));
#pragma unroll
      for (int off = 1; off < 16; off <<= 1) mt = fmaxf(mt, __shfl_xor(mt, off, 64));
      float mnew = fmaxf(m_run[r], mt);
      float corr = __expf(m_run[r] - mnew);
      float sum = 0.f;
#pragma unroll
      for (int j = 0; j < 4; ++j) {
        float pv = __expf(sacc[j][r] - mnew);
        p_val[j][r] = pv;
        sum += pv;
      }
#pragma unroll
      for (int off = 1; off < 16; off <<= 1) sum += __shfl_xor(sum, off, 64);
      l_run[r] = l_run[r] * corr + sum;
      m_run[r] = mnew;
#pragma unroll
      for (int dt = 0; dt < 8; ++dt) o[dt][r] *= corr;
    }

    // P -> LDS (bf16), per-wave buffer
#pragma unroll
    for (int j = 0; j < 4; ++j)
#pragma unroll
      for (int r = 0; r < 4; ++r) {
        int row = g * 4 + r, col = j * 16 + l15;
        *reinterpret_cast<__bf16*>(&P_base[row * 144 + col * 2]) = (__bf16)p_val[j][r];
      }

    // PV: O(16x128) += P(16x64) * V(64x128)
#pragma unroll
    for (int kc = 0; kc < 2; ++kc) {
      bf16x8 pa = *reinterpret_cast<const bf16x8*>(&P_base[l15 * 144 + kc * 64 + g * 16]);
#pragma unroll
      for (int dt = 0; dt < 8; ++dt) {
        int row = dt * 16 + l15;
        bf16x8 vb =
            *reinterpret_cast<const bf16x8*>(&smem[VT_OFF + row * 144 + kc * 64 + g * 16]);
        o[dt] = mfma16(pa, vb, o[dt]);
      }
    }
  }

  // epilogue: normalize and store bf16 to [b*S+q][h*128+d]
  float inv_l[4];
#pragma unroll
  for (int r = 0; r < 4; ++r) inv_l[r] = 1.0f / l_run[r];
  int qb = qt * 64 + w * 16 + g * 4;
#pragma unroll
  for (int dt = 0; dt < 8; ++dt)
#pragma unroll
    for (int r = 0; r < 4; ++r) {
      int q = qb + r;
      outp[(size_t)(b * S_ + q) * D_ + h * DK_ + dt * 16 + l15] =
          (__bf16)(o[dt][r] * inv_l[r]);
    }
}

// ---------------- launch ----------------
extern "C" void kernel_launch(void* const* d_in, const int* in_sizes, int n_in,
                              void* d_out, int out_size, void* d_ws, size_t ws_size,
                              hipStream_t stream) {
  const float* x     = (const float*)d_in[0];
  // d_in[1] = mask (all ones, unused by reference math)
  const float* w_qkv = (const float*)d_in[2];
  const float* b_qkv = (const float*)d_in[3];
  const float* w_o   = (const float*)d_in[4];
  const float* b_o   = (const float*)d_in[5];
  float* out = (float*)d_out;

  uint8_t* ws = (uint8_t*)d_ws;
  // layout: xbf 16MB | wqkvbf 24MB | wobf 8MB | qkvbf 48MB  (~100.7MB total)
  __bf16* xbf    = (__bf16*)(ws);
  __bf16* wqkvbf = (__bf16*)(ws + 16777216);
  __bf16* wobf   = (__bf16*)(ws + 16777216 + 25165824);
  __bf16* qkvbf  = (__bf16*)(ws + 50331648);
  __bf16* vtbf   = (__bf16*)wqkvbf;  // alias: w_qkv bf16 dead after GEMM1
  __bf16* attnbf = (__bf16*)xbf;     // alias: x bf16 dead after GEMM1

  cvt_f32_bf16<<<2048, 256, 0, stream>>>(x, xbf, B_ * S_ * D_);
  cvt_f32_bf16<<<2048, 256, 0, stream>>>(w_qkv, wqkvbf, E3_ * D_);
  cvt_f32_bf16<<<2048, 256, 0, stream>>>(w_o, wobf, D_ * D_);

  dim3 g1(E3_ / 128, (B_ * S_) / 128);  // 48 x 32
  gemm_bt<true><<<g1, 256, 0, stream>>>(xbf, wqkvbf, b_qkv, qkvbf, B_ * S_, E3_, D_);

  dim3 gt(S_ / 64, DK_ / 64, B_ * H_);  // 32 x 2 x 32
  transpose_v<<<gt, 256, 0, stream>>>(qkvbf, vtbf);

  dim3 ga(S_ / 64, B_ * H_);  // 32 x 32
  attn_fwd<<<ga, 256, 0, stream>>>(qkvbf, vtbf, attnbf);

  dim3 g2(D_ / 128, (B_ * S_) / 128);  // 16 x 32
  gemm_bt<false><<<g2, 256, 0, stream>>>(attnbf, wobf, b_o, out, B_ * S_, D_, D_);
}